// Round 7
// baseline (346.857 us; speedup 1.0000x reference)
//
#include <hip/hip_runtime.h>
#include <hip/hip_bf16.h>

#define B_ 64
#define T_ 512
#define LOG2E 1.4426950408889634f
#define PHASE_STEPS 16
#define NPHASE (T_/PHASE_STEPS)

typedef __attribute__((ext_vector_type(8))) short short8;
typedef __attribute__((ext_vector_type(4))) float f32x4;

__device__ __forceinline__ float fast_exp2(float x){ return __builtin_amdgcn_exp2f(x); }
__device__ __forceinline__ float fast_rcp(float x){ return __builtin_amdgcn_rcpf(x); }
__device__ __forceinline__ float sigmoidf_(float x){ return fast_rcp(1.0f + fast_exp2(-x*LOG2E)); }
__device__ __forceinline__ unsigned short f2bf(float f){
  union{float f; unsigned u;} v; v.f = f;
  unsigned r = v.u + 0x7fffu + ((v.u>>16)&1u);
  return (unsigned short)(r>>16);
}

// DPP butterfly add over 8-lane groups
template<int CTRL>
__device__ __forceinline__ float dpp_xadd(float x){
  int y = __builtin_amdgcn_update_dpp(0, __float_as_int(x), CTRL, 0xf, 0xf, true);
  return x + __int_as_float(y);
}
__device__ __forceinline__ float dpp_sum8(float x){
  x = dpp_xadd<0xB1>(x);   // quad_perm xor1
  x = dpp_xadd<0x4E>(x);   // quad_perm xor2
  x = dpp_xadd<0x141>(x);  // row_half_mirror
  return x;
}

// ---- device-scope producer/consumer primitives (cross-XCD safe) ------------------------
__device__ __forceinline__ unsigned ld_acq(unsigned* p){
  return __hip_atomic_load(p, __ATOMIC_ACQUIRE, __HIP_MEMORY_SCOPE_AGENT);
}
__device__ __forceinline__ void spin_ge(unsigned* p, unsigned tgt){
  while (ld_acq(p) < tgt) __builtin_amdgcn_s_sleep(4);
}
__device__ __forceinline__ void flag_add(unsigned* p){
  __threadfence();  // agent fence: make prior block stores device-visible
  __hip_atomic_fetch_add(p, 1u, __ATOMIC_RELEASE, __HIP_MEMORY_SCOPE_AGENT);
}

// ---------------- scan role: waves0-3 compute, wave4 DMA; chunk-gated -------------------
template<int STORE_ALL>
__device__ __forceinline__ void scan_role(const float* __restrict__ P,
    float* __restrict__ Rout, int bh,
    unsigned* cnt_in, unsigned tgt, unsigned* cnt_out, char* smemc)
{
  float (*buf)[PHASE_STEPS*288] = (float (*)[PHASE_STEPS*288])smemc;
  int tid = threadIdx.x;
  int wv = tid >> 6, lane = tid & 63;
  const float* Pb = P + (long)bh*512*288;
  if (wv == 4){
    #pragma unroll 1
    for (int p = 0; p < NPHASE; ++p){
      spin_ge(&cnt_in[p], tgt);
      const float4* src = (const float4*)(Pb + (long)p*PHASE_STEPS*288);
      float4* dst = (float4*)buf[p&1];
      float4 tmp[18];
      #pragma unroll
      for (int i=0;i<18;++i) tmp[i] = src[lane + i*64];
      #pragma unroll
      for (int i=0;i<18;++i) dst[lane + i*64] = tmp[i];
      __syncthreads();            // barrier p+1: buf[p&1] ready
    }
    __syncthreads();              // final barrier (#33)
  } else {
    int g = lane >> 3, slot = lane & 7;
    int bl = wv*8 + g;
    int batch = bh*32 + bl;
    float m0=0.f, m1=0.f, m2=0.f;
    __syncthreads();              // barrier 1: buf0 ready
    #pragma unroll 1
    for (int p = 0; p < NPHASE; ++p){
      const float* bp = buf[p&1];
      float pp[3][9];
      #pragma unroll
      for (int j=0;j<9;++j){ pp[0][j] = bp[j*32+bl]; pp[1][j] = bp[288 + j*32+bl]; }
      #pragma unroll
      for (int s=0;s<PHASE_STEPS;++s){
        if (s+2 < PHASE_STEPS){
          #pragma unroll
          for (int j=0;j<9;++j) pp[(s+2)%3][j] = bp[(s+2)*288 + j*32 + bl];
        }
        const float* pv = pp[s%3];
        float sc = fmaf(m2, pv[2], fmaf(m1, pv[1], m0*pv[0]));
        float pe = fast_exp2(sc);
        float S = dpp_sum8(pe);
        float rinv = fast_rcp(S);
        float w = pe * rinv;
        if (STORE_ALL){
          float r0 = dpp_sum8(pe*m0);
          float r1 = dpp_sum8(pe*m1);
          float r2 = dpp_sum8(pe*m2);
          float rsel = (slot==0) ? r0 : ((slot==1) ? r1 : r2);
          rsel *= rinv;
          if (slot < 3) Rout[((p*PHASE_STEPS+s)*3 + slot)*64 + batch] = rsel;
        } else if (s == PHASE_STEPS-1 && p == NPHASE-1){
          float r0 = dpp_sum8(pe*m0);
          float r1 = dpp_sum8(pe*m1);
          float r2 = dpp_sum8(pe*m2);
          float rsel = (slot==0) ? r0 : ((slot==1) ? r1 : r2);
          rsel *= rinv;
          if (slot < 3) Rout[slot*64 + batch] = rsel;
        }
        float v0=pv[3], v1=pv[4], v2=pv[5], e0=pv[6], e1=pv[7], e2=pv[8];
        m0 = fmaf(w, fmaf(-e0, m0, v0), m0);
        m1 = fmaf(w, fmaf(-e1, m1, v1), m1);
        m2 = fmaf(w, fmaf(-e2, m2, v2), m2);
      }
      __syncthreads();            // barrier p+2: phase-p stores drained block-wide
      if (cnt_out && tid == 0) flag_add(&cnt_out[p]);
    }
  }
}

// ---------------- mega kernel: 256 blocks x 320 threads ---------------------------------
// blocks 0,1: scan1(bh) | blocks 2,3: scan2(bh) | blocks 4..255: workers
__global__ __launch_bounds__(320,1) void k_mega(
    const float* __restrict__ X,
    const float* __restrict__ W1k, const float* __restrict__ b1k,
    const float* __restrict__ W1w, const float* __restrict__ b1w,
    const float* __restrict__ W1g, const float* __restrict__ b1g,
    const float* __restrict__ W1o, const float* __restrict__ b1o,
    const float* __restrict__ W2k, const float* __restrict__ b2k,
    const float* __restrict__ W2w, const float* __restrict__ b2w,
    const float* __restrict__ W2g, const float* __restrict__ b2g,
    float* __restrict__ P1, float* __restrict__ R1,
    float* __restrict__ P2, float* __restrict__ O1last, float* __restrict__ R2F,
    unsigned short* __restrict__ W1oTb, unsigned short* __restrict__ W2cTb,
    unsigned* __restrict__ flags)
{
  __shared__ __align__(16) char smem[40448];
  unsigned* proj_cnt  = flags;        // [32], target 16 tiles/chunk
  unsigned* r1_cnt    = flags + 32;   // [32], target 2 blocks
  unsigned* fused_cnt = flags + 64;   // [32], target 64 tiles/chunk
  unsigned* prep_cnt  = flags + 96;   // [1],  target NW
  int role = blockIdx.x;
  int tid = threadIdx.x;

  if (role < 2){ scan_role<1>(P1, R1, role, proj_cnt, 16, r1_cnt, smem); return; }
  if (role < 4){ scan_role<0>(P2, R2F, role-2, fused_cnt, 64, nullptr, smem); return; }

  int wid = role - 4;
  int NW = (int)gridDim.x - 4;

  // ---- prep: bf16 weight repack -------------------------------------------------------
  {
    int NT = NW*320;
    int gthread = wid*320 + tid;
    for (int x = gthread; x < 65536; x += NT){
      int n = x >> 7, k = x & 127;
      W1oTb[x] = f2bf(W1o[k*512 + n]);
    }
    for (int x = gthread; x < 8192; x += NT){
      int j = x >> 9, cc = x & 511;
      float v = 0.f;
      if (j < 3) v = W2k[cc*3+j];
      else if (j < 6) v = W2w[cc*3+j-3];
      else if (j < 9) v = W2g[cc*3+j-6];
      W2cTb[x] = f2bf(v);
    }
    __syncthreads();
    if (tid == 0) flag_add(prep_cnt);
  }

  // ---- proj phase: tile = (chunk c<32, b-quad q<16) = 64 rows x 9 outs; 512 tiles ------
  {
    float* A  = (float*)smem;             // 64*132 floats
    float* Wc = (float*)(smem + 33792);   // 1536 floats
    float* bb = (float*)(smem + 39936);   // 9 floats
    for (int w_=tid; w_<1152; w_+=320){
      int k=w_/9, j=w_%9; float val;
      if (j<3) val=W1k[k*3+j]; else if (j<6) val=W1w[k*3+j-3]; else val=W1g[k*3+j-6];
      Wc[k*12+j]=val;
    }
    if (tid<9){ float v; if(tid<3)v=b1k[tid]; else if(tid<6)v=b1w[tid-3]; else v=b1g[tid-6]; bb[tid]=v; }
    __syncthreads();
    #pragma unroll 1
    for (int i = wid; i < 512; i += NW){   // FIX (was 2048): 32 chunks x 16 quads
      int c = i >> 4, q = i & 15;
      if (tid < 256){
        #pragma unroll
        for (int it=0; it<8; ++it){
          int f4 = tid + it*256;
          int blk = f4 >> 9, off = f4 & 511;
          const float4* src = (const float4*)(X + ((long)(4*q+blk)*512 + 16*c)*128);
          float4 v = src[off];
          int f = off*4, trow = f>>7, k = f&127;
          int row = blk*16 + trow;
          A[row*132+k]=v.x; A[row*132+k+1]=v.y; A[row*132+k+2]=v.z; A[row*132+k+3]=v.w;
        }
      }
      __syncthreads();
      for (int o = tid; o < 576; o += 320){
        int row=o/9, j=o%9;
        float acc = bb[j];
        #pragma unroll 8
        for (int k=0;k<128;++k) acc = fmaf(A[row*132+k], Wc[k*12+j], acc);
        if (j<3) acc *= LOG2E;
        else if (j<6) acc *= 0.1f;
        else acc = 0.1f*sigmoidf_(acc);
        int b = 4*q + (row>>4), t = 16*c + (row&15);
        P1[((long)(b>>5)*512 + t)*288 + j*32 + (b&31)] = acc;
      }
      __syncthreads();
      if (tid == 0) flag_add(&proj_cnt[c]);
    }
  }

  // ---- wait: all workers finished prep (W1oTb/W2cTb complete) ---------------------------
  if (tid == 0) spin_ge(prep_cnt, (unsigned)NW);
  __syncthreads();

  // ---- fused phase: tile = (chunk c<32, batch b<64) = 2048 tiles, gated on r1_cnt[c] ----
  {
    float* pSum = (float*)smem;                       // 1024 floats
    float* rdS  = (float*)(smem + 4096);              // 48 floats
    unsigned short* o1b = (unsigned short*)(smem + 4352);  // 16*520 shorts
    int w = tid >> 6, lane = tid & 63;
    int n16 = lane & 15, g4 = lane >> 4;
    #pragma unroll 1
    for (int i = wid; i < 2048; i += NW){
      int c = i >> 6, b = i & 63;
      if (tid == 0) spin_ge(&r1_cnt[c], 2);
      __syncthreads();
      int t0 = c*16;
      long r0 = (long)b*512 + t0;
      if (tid < 48){
        int ii = tid/3, d = tid%3;
        rdS[tid] = R1[((t0+ii)*3+d)*64 + b];
      }
      short8 afr[4];
      if (w < 4){
        const float* Xrow = X + (r0 + n16)*128;
        #pragma unroll
        for (int q=0;q<4;++q){
          f32x4 x0 = *(const f32x4*)(Xrow + q*32 + g4*8);
          f32x4 x1 = *(const f32x4*)(Xrow + q*32 + g4*8 + 4);
          short8 a;
          a[0]=(short)f2bf(x0[0]); a[1]=(short)f2bf(x0[1]);
          a[2]=(short)f2bf(x0[2]); a[3]=(short)f2bf(x0[3]);
          a[4]=(short)f2bf(x1[0]); a[5]=(short)f2bf(x1[1]);
          a[6]=(short)f2bf(x1[2]); a[7]=(short)f2bf(x1[3]);
          afr[q]=a;
        }
      }
      __syncthreads();
      if (w < 4){
        f32x4 ra = *(const f32x4*)(rdS + g4*12);
        f32x4 rb = *(const f32x4*)(rdS + g4*12 + 4);
        f32x4 rc = *(const f32x4*)(rdS + g4*12 + 8);
        float rd0[4] = { ra[0], ra[3], rb[2], rc[1] };
        float rd1[4] = { ra[1], rb[0], rb[3], rc[2] };
        float rd2[4] = { ra[2], rb[1], rc[0], rc[3] };
        #pragma unroll
        for (int tt=0; tt<8; ++tt){
          int gc = w*128 + tt*16 + n16;
          f32x4 acc = {0.f,0.f,0.f,0.f};
          #pragma unroll
          for (int q=0;q<4;++q){
            short8 bf = *(const short8*)(W1oTb + gc*128 + q*32 + g4*8);
            acc = __builtin_amdgcn_mfma_f32_16x16x32_bf16(afr[q], bf, acc, 0,0,0);
          }
          float bias = b1o[gc];
          float wr0 = W1o[128*512+gc], wr1 = W1o[129*512+gc], wr2 = W1o[130*512+gc];
          #pragma unroll
          for (int reg=0; reg<4; ++reg){
            int rowloc = g4*4 + reg;
            float z = acc[reg] + bias + rd0[reg]*wr0 + rd1[reg]*wr1 + rd2[reg]*wr2;
            float o1 = sigmoidf_(z);
            o1b[rowloc*520 + gc] = f2bf(o1);
            if (c == 31 && rowloc == 15) O1last[b*512 + gc] = o1;
          }
        }
        f32x4 accP = {0.f,0.f,0.f,0.f};
        #pragma unroll
        for (int q2=0; q2<4; ++q2){
          int kk = w*128 + q2*32;
          short8 a2 = *(const short8*)(o1b + n16*520 + kk + g4*8);
          short8 bb2 = *(const short8*)(W2cTb + n16*512 + kk + g4*8);
          accP = __builtin_amdgcn_mfma_f32_16x16x32_bf16(a2, bb2, accP, 0,0,0);
        }
        #pragma unroll
        for (int reg=0;reg<4;++reg){
          int rowloc = g4*4+reg;
          pSum[w*256 + rowloc*16 + n16] = accP[reg];
        }
      }
      __syncthreads();
      if (tid < 144){
        int r = tid/9, j = tid%9;
        float s = pSum[r*16+j] + pSum[256+r*16+j] + pSum[512+r*16+j] + pSum[768+r*16+j];
        float outv;
        if (j<3){ s += b2k[j]; outv = s*LOG2E; }
        else if (j<6){ s += b2w[j-3]; outv = 0.1f*s; }
        else { s += b2g[j-6]; outv = 0.1f*sigmoidf_(s); }
        int t = t0 + r;
        P2[((long)(b>>5)*512 + t)*288 + j*32 + (b&31)] = outv;
      }
      __syncthreads();
      if (tid == 0) flag_add(&fused_cnt[c]);
    }
  }
}

// ---------------- k_final: Opart + read2 correction + sigmoid ---------------------------
__global__ __launch_bounds__(128) void k_final(const float* __restrict__ O1last,
    const float* __restrict__ R2F, const float* __restrict__ W2o,
    const float* __restrict__ b2o, float* __restrict__ out)
{
  __shared__ __align__(16) float s2[512];
  int b = blockIdx.x, tid = threadIdx.x;
  ((float4*)s2)[tid] = ((const float4*)(O1last + b*512))[tid];
  __syncthreads();
  float acc = b2o[tid];
  #pragma unroll 8
  for (int n=0;n<512;++n) acc = fmaf(s2[n], W2o[n*128+tid], acc);
  float r0 = R2F[b], r1 = R2F[64+b], r2 = R2F[128+b];
  acc += r0*W2o[512*128+tid] + r1*W2o[513*128+tid] + r2*W2o[514*128+tid];
  out[b*128+tid] = sigmoidf_(acc);
}

extern "C" void kernel_launch(void* const* d_in, const int* in_sizes, int n_in,
                              void* d_out, int out_size, void* d_ws, size_t ws_size,
                              hipStream_t stream)
{
  const float* X  = (const float*)d_in[0];
  const float* W1k= (const float*)d_in[1]; const float* b1k=(const float*)d_in[2];
  const float* W1w= (const float*)d_in[3]; const float* b1w=(const float*)d_in[4];
  const float* W1g= (const float*)d_in[5]; const float* b1g=(const float*)d_in[6];
  const float* W1o= (const float*)d_in[7]; const float* b1o=(const float*)d_in[8];
  const float* W2k= (const float*)d_in[9]; const float* b2k=(const float*)d_in[10];
  const float* W2w= (const float*)d_in[11]; const float* b2w=(const float*)d_in[12];
  const float* W2g= (const float*)d_in[13]; const float* b2g=(const float*)d_in[14];
  const float* W2o= (const float*)d_in[15]; const float* b2o=(const float*)d_in[16];

  float* ws = (float*)d_ws;
  float* P1     = ws;               // 2*512*288  = 294912
  float* R1     = P1 + 294912;      // 512*3*64   =  98304
  float* P2     = R1 + 98304;       // 2*512*288  = 294912
  float* O1last = P2 + 294912;      // 64*512     =  32768
  float* R2F    = O1last + 32768;   // 3*64       =    192
  unsigned short* W1oTb = (unsigned short*)(R2F + 192);   // 512*128 bf16 = 32768 f
  unsigned short* W2cTb = W1oTb + 65536;                  // 16*512 bf16  =  4096 f
  unsigned* flags = (unsigned*)(R2F + 192 + 32768 + 4096);  // 128 u32
  float* out    = (float*)d_out;

  hipMemsetAsync(flags, 0, 512, stream);
  hipLaunchKernelGGL(k_mega, dim3(256), dim3(320), 0, stream,
                     X, W1k,b1k, W1w,b1w, W1g,b1g, W1o,b1o,
                     W2k,b2k, W2w,b2w, W2g,b2g,
                     P1, R1, P2, O1last, R2F, W1oTb, W2cTb, flags);
  hipLaunchKernelGGL(k_final, dim3(64), dim3(128), 0, stream,
                     O1last, R2F, W2o, b2o, out);
}

// Round 8
// 316.879 us; speedup vs baseline: 1.0946x; 1.0946x over previous
//
#include <hip/hip_runtime.h>
#include <hip/hip_bf16.h>

#define B_ 64
#define T_ 512
#define LOG2E 1.4426950408889634f
#define PHASE_STEPS 16
#define NPHASE (T_/PHASE_STEPS)

typedef __attribute__((ext_vector_type(8))) short short8;
typedef __attribute__((ext_vector_type(4))) float f32x4;

__device__ __forceinline__ float fast_exp2(float x){ return __builtin_amdgcn_exp2f(x); }
__device__ __forceinline__ float fast_rcp(float x){ return __builtin_amdgcn_rcpf(x); }
__device__ __forceinline__ float sigmoidf_(float x){ return fast_rcp(1.0f + fast_exp2(-x*LOG2E)); }
__device__ __forceinline__ unsigned short f2bf(float f){
  union{float f; unsigned u;} v; v.f = f;
  unsigned r = v.u + 0x7fffu + ((v.u>>16)&1u);
  return (unsigned short)(r>>16);
}
template<typename T>
__device__ __forceinline__ void st_nt(T* p, T v){ __builtin_nontemporal_store(v, p); }

// DPP butterfly add over 8-lane groups
template<int CTRL>
__device__ __forceinline__ float dpp_xadd(float x){
  int y = __builtin_amdgcn_update_dpp(0, __float_as_int(x), CTRL, 0xf, 0xf, true);
  return x + __int_as_float(y);
}
__device__ __forceinline__ float dpp_sum8(float x){
  x = dpp_xadd<0xB1>(x);   // quad_perm xor1
  x = dpp_xadd<0x4E>(x);   // quad_perm xor2
  x = dpp_xadd<0x141>(x);  // row_half_mirror
  return x;
}

// ---- device-scope producer/consumer primitives (cross-XCD safe, invalidate-frugal) -----
// RELAXED agent-scope polls are line-granular at the coherence point (no L2 flash-inv);
// ONE acquire fence after the spin succeeds. Release = one fence + relaxed RMW.
__device__ __forceinline__ unsigned ld_rlx(unsigned* p){
  return __hip_atomic_load(p, __ATOMIC_RELAXED, __HIP_MEMORY_SCOPE_AGENT);
}
__device__ __forceinline__ void spin_ge(unsigned* p, unsigned tgt){
  while (ld_rlx(p) < tgt) __builtin_amdgcn_s_sleep(2);
  __builtin_amdgcn_fence(__ATOMIC_ACQUIRE, "agent");
}
__device__ __forceinline__ void flag_add(unsigned* p){
  __builtin_amdgcn_fence(__ATOMIC_RELEASE, "agent");
  __hip_atomic_fetch_add(p, 1u, __ATOMIC_RELAXED, __HIP_MEMORY_SCOPE_AGENT);
}

// ---------------- scan role: waves0-3 compute, wave4 DMA; chunk-gated -------------------
template<int STORE_ALL>
__device__ __forceinline__ void scan_role(const float* __restrict__ P,
    float* __restrict__ Rout, int bh,
    unsigned* cnt_in, unsigned tgt, unsigned* cnt_out, char* smemc)
{
  float (*buf)[PHASE_STEPS*288] = (float (*)[PHASE_STEPS*288])smemc;
  int tid = threadIdx.x;
  int wv = tid >> 6, lane = tid & 63;
  const float* Pb = P + (long)bh*512*288;
  if (wv == 4){
    #pragma unroll 1
    for (int p = 0; p < NPHASE; ++p){
      spin_ge(&cnt_in[p], tgt);
      const float4* src = (const float4*)(Pb + (long)p*PHASE_STEPS*288);
      float4* dst = (float4*)buf[p&1];
      float4 tmp[18];
      #pragma unroll
      for (int i=0;i<18;++i) tmp[i] = src[lane + i*64];
      #pragma unroll
      for (int i=0;i<18;++i) dst[lane + i*64] = tmp[i];
      __syncthreads();            // barrier p+1: buf[p&1] ready
    }
    __syncthreads();              // final barrier (#33)
  } else {
    int g = lane >> 3, slot = lane & 7;
    int bl = wv*8 + g;
    int batch = bh*32 + bl;
    float m0=0.f, m1=0.f, m2=0.f;
    __syncthreads();              // barrier 1: buf0 ready
    #pragma unroll 1
    for (int p = 0; p < NPHASE; ++p){
      const float* bp = buf[p&1];
      float pp[3][9];
      #pragma unroll
      for (int j=0;j<9;++j){ pp[0][j] = bp[j*32+bl]; pp[1][j] = bp[288 + j*32+bl]; }
      #pragma unroll
      for (int s=0;s<PHASE_STEPS;++s){
        if (s+2 < PHASE_STEPS){
          #pragma unroll
          for (int j=0;j<9;++j) pp[(s+2)%3][j] = bp[(s+2)*288 + j*32 + bl];
        }
        const float* pv = pp[s%3];
        float sc = fmaf(m2, pv[2], fmaf(m1, pv[1], m0*pv[0]));
        float pe = fast_exp2(sc);
        float S = dpp_sum8(pe);
        float rinv = fast_rcp(S);
        float w = pe * rinv;
        if (STORE_ALL){
          float r0 = dpp_sum8(pe*m0);
          float r1 = dpp_sum8(pe*m1);
          float r2 = dpp_sum8(pe*m2);
          float rsel = (slot==0) ? r0 : ((slot==1) ? r1 : r2);
          rsel *= rinv;
          if (slot < 3) st_nt(&Rout[((p*PHASE_STEPS+s)*3 + slot)*64 + batch], rsel);
        } else if (s == PHASE_STEPS-1 && p == NPHASE-1){
          float r0 = dpp_sum8(pe*m0);
          float r1 = dpp_sum8(pe*m1);
          float r2 = dpp_sum8(pe*m2);
          float rsel = (slot==0) ? r0 : ((slot==1) ? r1 : r2);
          rsel *= rinv;
          if (slot < 3) st_nt(&Rout[slot*64 + batch], rsel);
        }
        float v0=pv[3], v1=pv[4], v2=pv[5], e0=pv[6], e1=pv[7], e2=pv[8];
        m0 = fmaf(w, fmaf(-e0, m0, v0), m0);
        m1 = fmaf(w, fmaf(-e1, m1, v1), m1);
        m2 = fmaf(w, fmaf(-e2, m2, v2), m2);
      }
      __syncthreads();            // barrier p+2: phase-p stores drained block-wide
      if (cnt_out && tid == 0) flag_add(&cnt_out[p]);
    }
  }
}

// ---------------- mega kernel: 256 blocks x 320 threads ---------------------------------
// blocks 0,1: scan1(bh) | blocks 2,3: scan2(bh) | blocks 4..255: workers
__global__ __launch_bounds__(320,1) void k_mega(
    const float* __restrict__ X,
    const float* __restrict__ W1k, const float* __restrict__ b1k,
    const float* __restrict__ W1w, const float* __restrict__ b1w,
    const float* __restrict__ W1g, const float* __restrict__ b1g,
    const float* __restrict__ W1o, const float* __restrict__ b1o,
    const float* __restrict__ W2k, const float* __restrict__ b2k,
    const float* __restrict__ W2w, const float* __restrict__ b2w,
    const float* __restrict__ W2g, const float* __restrict__ b2g,
    float* __restrict__ P1, float* __restrict__ R1,
    float* __restrict__ P2, float* __restrict__ O1last, float* __restrict__ R2F,
    unsigned short* __restrict__ W1oTb, unsigned short* __restrict__ W2cTb,
    unsigned* __restrict__ flags)
{
  __shared__ __align__(16) char smem[40448];
  unsigned* proj_cnt  = flags;        // [32], target 16 tiles/chunk
  unsigned* r1_cnt    = flags + 32;   // [32], target 2 blocks
  unsigned* fused_cnt = flags + 64;   // [32], target 64 tiles/chunk
  unsigned* prep_cnt  = flags + 96;   // [1],  target NW
  int role = blockIdx.x;
  int tid = threadIdx.x;

  if (role < 2){ scan_role<1>(P1, R1, role, proj_cnt, 16, r1_cnt, smem); return; }
  if (role < 4){ scan_role<0>(P2, R2F, role-2, fused_cnt, 64, nullptr, smem); return; }

  int wid = role - 4;
  int NW = (int)gridDim.x - 4;

  // ---- prep: bf16 weight repack -------------------------------------------------------
  {
    int NT = NW*320;
    int gthread = wid*320 + tid;
    for (int x = gthread; x < 65536; x += NT){
      int n = x >> 7, k = x & 127;
      st_nt(&W1oTb[x], f2bf(W1o[k*512 + n]));
    }
    for (int x = gthread; x < 8192; x += NT){
      int j = x >> 9, cc = x & 511;
      float v = 0.f;
      if (j < 3) v = W2k[cc*3+j];
      else if (j < 6) v = W2w[cc*3+j-3];
      else if (j < 9) v = W2g[cc*3+j-6];
      st_nt(&W2cTb[x], f2bf(v));
    }
    __syncthreads();
    if (tid == 0) flag_add(prep_cnt);
  }

  // ---- proj phase: tile = (chunk c<32, b-quad q<16) = 64 rows x 9 outs; 512 tiles ------
  {
    float* A  = (float*)smem;             // 64*132 floats
    float* Wc = (float*)(smem + 33792);   // 1536 floats
    float* bb = (float*)(smem + 39936);   // 9 floats
    for (int w_=tid; w_<1152; w_+=320){
      int k=w_/9, j=w_%9; float val;
      if (j<3) val=W1k[k*3+j]; else if (j<6) val=W1w[k*3+j-3]; else val=W1g[k*3+j-6];
      Wc[k*12+j]=val;
    }
    if (tid<9){ float v; if(tid<3)v=b1k[tid]; else if(tid<6)v=b1w[tid-3]; else v=b1g[tid-6]; bb[tid]=v; }
    __syncthreads();
    #pragma unroll 1
    for (int i = wid; i < 512; i += NW){   // 32 chunks x 16 quads
      int c = i >> 4, q = i & 15;
      if (tid < 256){
        #pragma unroll
        for (int it=0; it<8; ++it){
          int f4 = tid + it*256;
          int blk = f4 >> 9, off = f4 & 511;
          const float4* src = (const float4*)(X + ((long)(4*q+blk)*512 + 16*c)*128);
          float4 v = src[off];
          int f = off*4, trow = f>>7, k = f&127;
          int row = blk*16 + trow;
          A[row*132+k]=v.x; A[row*132+k+1]=v.y; A[row*132+k+2]=v.z; A[row*132+k+3]=v.w;
        }
      }
      __syncthreads();
      for (int o = tid; o < 576; o += 320){
        int row=o/9, j=o%9;
        float acc = bb[j];
        #pragma unroll 8
        for (int k=0;k<128;++k) acc = fmaf(A[row*132+k], Wc[k*12+j], acc);
        if (j<3) acc *= LOG2E;
        else if (j<6) acc *= 0.1f;
        else acc = 0.1f*sigmoidf_(acc);
        int b = 4*q + (row>>4), t = 16*c + (row&15);
        st_nt(&P1[((long)(b>>5)*512 + t)*288 + j*32 + (b&31)], acc);
      }
      __syncthreads();
      if (tid == 0) flag_add(&proj_cnt[c]);
    }
  }

  // ---- wait: all workers finished prep (W1oTb/W2cTb complete) ---------------------------
  if (tid == 0) spin_ge(prep_cnt, (unsigned)NW);
  __syncthreads();

  // ---- fused phase: tile = (chunk c<32, batch b<64) = 2048 tiles, gated on r1_cnt[c] ----
  {
    float* pSum = (float*)smem;                       // 1024 floats
    float* rdS  = (float*)(smem + 4096);              // 48 floats
    unsigned short* o1b = (unsigned short*)(smem + 4352);  // 16*520 shorts
    int w = tid >> 6, lane = tid & 63;
    int n16 = lane & 15, g4 = lane >> 4;
    #pragma unroll 1
    for (int i = wid; i < 2048; i += NW){
      int c = i >> 6, b = i & 63;
      if (tid == 0) spin_ge(&r1_cnt[c], 2);
      __syncthreads();
      int t0 = c*16;
      long r0 = (long)b*512 + t0;
      if (tid < 48){
        int ii = tid/3, d = tid%3;
        rdS[tid] = R1[((t0+ii)*3+d)*64 + b];
      }
      short8 afr[4];
      if (w < 4){
        const float* Xrow = X + (r0 + n16)*128;
        #pragma unroll
        for (int q=0;q<4;++q){
          f32x4 x0 = *(const f32x4*)(Xrow + q*32 + g4*8);
          f32x4 x1 = *(const f32x4*)(Xrow + q*32 + g4*8 + 4);
          short8 a;
          a[0]=(short)f2bf(x0[0]); a[1]=(short)f2bf(x0[1]);
          a[2]=(short)f2bf(x0[2]); a[3]=(short)f2bf(x0[3]);
          a[4]=(short)f2bf(x1[0]); a[5]=(short)f2bf(x1[1]);
          a[6]=(short)f2bf(x1[2]); a[7]=(short)f2bf(x1[3]);
          afr[q]=a;
        }
      }
      __syncthreads();
      if (w < 4){
        f32x4 ra = *(const f32x4*)(rdS + g4*12);
        f32x4 rb = *(const f32x4*)(rdS + g4*12 + 4);
        f32x4 rc = *(const f32x4*)(rdS + g4*12 + 8);
        float rd0[4] = { ra[0], ra[3], rb[2], rc[1] };
        float rd1[4] = { ra[1], rb[0], rb[3], rc[2] };
        float rd2[4] = { ra[2], rb[1], rc[0], rc[3] };
        #pragma unroll
        for (int tt=0; tt<8; ++tt){
          int gc = w*128 + tt*16 + n16;
          f32x4 acc = {0.f,0.f,0.f,0.f};
          #pragma unroll
          for (int q=0;q<4;++q){
            short8 bf = *(const short8*)(W1oTb + gc*128 + q*32 + g4*8);
            acc = __builtin_amdgcn_mfma_f32_16x16x32_bf16(afr[q], bf, acc, 0,0,0);
          }
          float bias = b1o[gc];
          float wr0 = W1o[128*512+gc], wr1 = W1o[129*512+gc], wr2 = W1o[130*512+gc];
          #pragma unroll
          for (int reg=0; reg<4; ++reg){
            int rowloc = g4*4 + reg;
            float z = acc[reg] + bias + rd0[reg]*wr0 + rd1[reg]*wr1 + rd2[reg]*wr2;
            float o1 = sigmoidf_(z);
            o1b[rowloc*520 + gc] = f2bf(o1);
            if (c == 31 && rowloc == 15) st_nt(&O1last[b*512 + gc], o1);
          }
        }
        f32x4 accP = {0.f,0.f,0.f,0.f};
        #pragma unroll
        for (int q2=0; q2<4; ++q2){
          int kk = w*128 + q2*32;
          short8 a2 = *(const short8*)(o1b + n16*520 + kk + g4*8);
          short8 bb2 = *(const short8*)(W2cTb + n16*512 + kk + g4*8);
          accP = __builtin_amdgcn_mfma_f32_16x16x32_bf16(a2, bb2, accP, 0,0,0);
        }
        #pragma unroll
        for (int reg=0;reg<4;++reg){
          int rowloc = g4*4+reg;
          pSum[w*256 + rowloc*16 + n16] = accP[reg];
        }
      }
      __syncthreads();
      if (tid < 144){
        int r = tid/9, j = tid%9;
        float s = pSum[r*16+j] + pSum[256+r*16+j] + pSum[512+r*16+j] + pSum[768+r*16+j];
        float outv;
        if (j<3){ s += b2k[j]; outv = s*LOG2E; }
        else if (j<6){ s += b2w[j-3]; outv = 0.1f*s; }
        else { s += b2g[j-6]; outv = 0.1f*sigmoidf_(s); }
        int t = t0 + r;
        st_nt(&P2[((long)(b>>5)*512 + t)*288 + j*32 + (b&31)], outv);
      }
      __syncthreads();
      if (tid == 0) flag_add(&fused_cnt[c]);
    }
  }
}

// ---------------- k_final: Opart + read2 correction + sigmoid ---------------------------
__global__ __launch_bounds__(128) void k_final(const float* __restrict__ O1last,
    const float* __restrict__ R2F, const float* __restrict__ W2o,
    const float* __restrict__ b2o, float* __restrict__ out)
{
  __shared__ __align__(16) float s2[512];
  int b = blockIdx.x, tid = threadIdx.x;
  ((float4*)s2)[tid] = ((const float4*)(O1last + b*512))[tid];
  __syncthreads();
  float acc = b2o[tid];
  #pragma unroll 8
  for (int n=0;n<512;++n) acc = fmaf(s2[n], W2o[n*128+tid], acc);
  float r0 = R2F[b], r1 = R2F[64+b], r2 = R2F[128+b];
  acc += r0*W2o[512*128+tid] + r1*W2o[513*128+tid] + r2*W2o[514*128+tid];
  out[b*128+tid] = sigmoidf_(acc);
}

extern "C" void kernel_launch(void* const* d_in, const int* in_sizes, int n_in,
                              void* d_out, int out_size, void* d_ws, size_t ws_size,
                              hipStream_t stream)
{
  const float* X  = (const float*)d_in[0];
  const float* W1k= (const float*)d_in[1]; const float* b1k=(const float*)d_in[2];
  const float* W1w= (const float*)d_in[3]; const float* b1w=(const float*)d_in[4];
  const float* W1g= (const float*)d_in[5]; const float* b1g=(const float*)d_in[6];
  const float* W1o= (const float*)d_in[7]; const float* b1o=(const float*)d_in[8];
  const float* W2k= (const float*)d_in[9]; const float* b2k=(const float*)d_in[10];
  const float* W2w= (const float*)d_in[11]; const float* b2w=(const float*)d_in[12];
  const float* W2g= (const float*)d_in[13]; const float* b2g=(const float*)d_in[14];
  const float* W2o= (const float*)d_in[15]; const float* b2o=(const float*)d_in[16];

  float* ws = (float*)d_ws;
  float* P1     = ws;               // 2*512*288  = 294912
  float* R1     = P1 + 294912;      // 512*3*64   =  98304
  float* P2     = R1 + 98304;       // 2*512*288  = 294912
  float* O1last = P2 + 294912;      // 64*512     =  32768
  float* R2F    = O1last + 32768;   // 3*64       =    192
  unsigned short* W1oTb = (unsigned short*)(R2F + 192);   // 512*128 bf16 = 32768 f
  unsigned short* W2cTb = W1oTb + 65536;                  // 16*512 bf16  =  4096 f
  unsigned* flags = (unsigned*)(R2F + 192 + 32768 + 4096);  // 128 u32
  float* out    = (float*)d_out;

  hipMemsetAsync(flags, 0, 512, stream);
  hipLaunchKernelGGL(k_mega, dim3(256), dim3(320), 0, stream,
                     X, W1k,b1k, W1w,b1w, W1g,b1g, W1o,b1o,
                     W2k,b2k, W2w,b2w, W2g,b2g,
                     P1, R1, P2, O1last, R2F, W1oTb, W2cTb, flags);
  hipLaunchKernelGGL(k_final, dim3(64), dim3(128), 0, stream,
                     O1last, R2F, W2o, b2o, out);
}

// Round 9
// 263.729 us; speedup vs baseline: 1.3152x; 1.2015x over previous
//
#include <hip/hip_runtime.h>
#include <hip/hip_bf16.h>

#define B_ 64
#define T_ 512
#define LOG2E 1.4426950408889634f
#define PHASE_STEPS 16
#define NPHASE (T_/PHASE_STEPS)

typedef __attribute__((ext_vector_type(8))) short short8;
typedef __attribute__((ext_vector_type(4))) float f32x4;

__device__ __forceinline__ float fast_exp2(float x){ return __builtin_amdgcn_exp2f(x); }
__device__ __forceinline__ float fast_rcp(float x){ return __builtin_amdgcn_rcpf(x); }
__device__ __forceinline__ float sigmoidf_(float x){ return fast_rcp(1.0f + fast_exp2(-x*LOG2E)); }
__device__ __forceinline__ unsigned short f2bf(float f){
  union{float f; unsigned u;} v; v.f = f;
  unsigned r = v.u + 0x7fffu + ((v.u>>16)&1u);
  return (unsigned short)(r>>16);
}
template<typename T>
__device__ __forceinline__ void st_nt(T* p, T v){ __builtin_nontemporal_store(v, p); }

// DPP butterfly add over 8-lane groups
template<int CTRL>
__device__ __forceinline__ float dpp_xadd(float x){
  int y = __builtin_amdgcn_update_dpp(0, __float_as_int(x), CTRL, 0xf, 0xf, true);
  return x + __int_as_float(y);
}
__device__ __forceinline__ float dpp_sum8(float x){
  x = dpp_xadd<0xB1>(x);   // quad_perm xor1
  x = dpp_xadd<0x4E>(x);   // quad_perm xor2
  x = dpp_xadd<0x141>(x);  // row_half_mirror
  return x;
}

// ---- sync primitives: relaxed agent atomics (bypass stale XCD L2); no acquire fences ---
__device__ __forceinline__ unsigned ld_rlx_u32(unsigned* p){
  return __hip_atomic_load(p, __ATOMIC_RELAXED, __HIP_MEMORY_SCOPE_AGENT);
}
__device__ __forceinline__ float ld_rlx_f32(const float* p){
  return __hip_atomic_load(p, __ATOMIC_RELAXED, __HIP_MEMORY_SCOPE_AGENT);
}
template<int SLP>
__device__ __forceinline__ void spin_rlx(unsigned* p, unsigned tgt){
  while (ld_rlx_u32(p) < tgt) __builtin_amdgcn_s_sleep(SLP);
  asm volatile("" ::: "memory");   // compiler fence; HW in-order issue gives load ordering
}
__device__ __forceinline__ void acq_fence(){ __builtin_amdgcn_fence(__ATOMIC_ACQUIRE, "agent"); }
__device__ __forceinline__ void flag_add(unsigned* p){
  __builtin_amdgcn_fence(__ATOMIC_RELEASE, "agent");   // nt payloads already at L3 -> cheap
  __hip_atomic_fetch_add(p, 1u, __ATOMIC_RELAXED, __HIP_MEMORY_SCOPE_AGENT);
}

// ---------------- scan role: waves0-3 compute, wave4 DMA; chunk-gated -------------------
// Producer-contiguous P layouts: per phase p and half bh, source slab = P + p*9216 + bh*4608,
// 4608 floats contiguous. IS_P1: u -> (q=u/576, row=(u%576)/9, j=u%9, bl=4q+(row>>4), s=row&15)
// else  : u -> (b'=u/144, s=(u%144)/9, j=u%9, bl=b').  LDS dst = s*288 + j*32 + bl.
template<int STORE_ALL, int IS_P1>
__device__ __forceinline__ void scan_role(const float* __restrict__ P,
    float* __restrict__ Rout, int bh,
    unsigned* cnt_in, unsigned tgt, unsigned* cnt_out, char* smemc)
{
  float (*buf)[PHASE_STEPS*288] = (float (*)[PHASE_STEPS*288])smemc;
  int tid = threadIdx.x;
  int wv = tid >> 6, lane = tid & 63;
  const float* Pb = P + bh*4608;
  if (wv == 4){
    #pragma unroll 1
    for (int p = 0; p < NPHASE; ++p){
      if (lane == 0) spin_rlx<1>(&cnt_in[p], tgt);
      asm volatile("" ::: "memory");
      const float* src = Pb + (long)p*9216;
      float tmp[72];
      #pragma unroll
      for (int i=0;i<18;++i){
        int u0 = 4*(lane + 64*i);
        #pragma unroll
        for (int k=0;k<4;++k) tmp[i*4+k] = ld_rlx_f32(src + u0 + k);
      }
      float* dst = buf[p&1];
      #pragma unroll
      for (int i=0;i<18;++i){
        #pragma unroll
        for (int k=0;k<4;++k){
          int u = 4*(lane + 64*i) + k;
          int bl, s, j;
          if (IS_P1){
            int q = u/576; int r = u - q*576; int row = r/9; j = r - row*9;
            bl = 4*q + (row>>4); s = row & 15;
          } else {
            int b2 = u/144; int r = u - b2*144; s = r/9; j = r - s*9; bl = b2;
          }
          dst[s*288 + j*32 + bl] = tmp[i*4+k];
        }
      }
      __syncthreads();            // barrier p+1: buf[p&1] ready
    }
    __syncthreads();              // final barrier (#33)
  } else {
    int g = lane >> 3, slot = lane & 7;
    int bl = wv*8 + g;
    int batch = bh*32 + bl;
    float m0=0.f, m1=0.f, m2=0.f;
    __syncthreads();              // barrier 1: buf0 ready
    #pragma unroll 1
    for (int p = 0; p < NPHASE; ++p){
      const float* bp = buf[p&1];
      float pp[3][9];
      #pragma unroll
      for (int j=0;j<9;++j){ pp[0][j] = bp[j*32+bl]; pp[1][j] = bp[288 + j*32+bl]; }
      #pragma unroll
      for (int s=0;s<PHASE_STEPS;++s){
        if (s+2 < PHASE_STEPS){
          #pragma unroll
          for (int j=0;j<9;++j) pp[(s+2)%3][j] = bp[(s+2)*288 + j*32 + bl];
        }
        const float* pv = pp[s%3];
        float sc = fmaf(m2, pv[2], fmaf(m1, pv[1], m0*pv[0]));
        float pe = fast_exp2(sc);
        float S = dpp_sum8(pe);
        float rinv = fast_rcp(S);
        float w = pe * rinv;
        if (STORE_ALL){
          float r0 = dpp_sum8(pe*m0);
          float r1 = dpp_sum8(pe*m1);
          float r2 = dpp_sum8(pe*m2);
          float rsel = (slot==0) ? r0 : ((slot==1) ? r1 : r2);
          rsel *= rinv;
          if (slot < 3) st_nt(&Rout[((p*PHASE_STEPS+s)*3 + slot)*64 + batch], rsel);
        } else if (s == PHASE_STEPS-1 && p == NPHASE-1){
          float r0 = dpp_sum8(pe*m0);
          float r1 = dpp_sum8(pe*m1);
          float r2 = dpp_sum8(pe*m2);
          float rsel = (slot==0) ? r0 : ((slot==1) ? r1 : r2);
          rsel *= rinv;
          if (slot < 3) st_nt(&Rout[slot*64 + batch], rsel);
        }
        float v0=pv[3], v1=pv[4], v2=pv[5], e0=pv[6], e1=pv[7], e2=pv[8];
        m0 = fmaf(w, fmaf(-e0, m0, v0), m0);
        m1 = fmaf(w, fmaf(-e1, m1, v1), m1);
        m2 = fmaf(w, fmaf(-e2, m2, v2), m2);
      }
      __syncthreads();            // barrier p+2: phase-p stores drained (vmcnt0 pre-barrier)
      if (cnt_out && tid == 0) flag_add(&cnt_out[p]);
    }
  }
}

// ---------------- mega kernel: 256 blocks x 320 threads ---------------------------------
// blocks 0,1: scan1(bh) | blocks 2,3: scan2(bh) | blocks 4..255: workers
__global__ __launch_bounds__(320,1) void k_mega(
    const float* __restrict__ X,
    const float* __restrict__ W1k, const float* __restrict__ b1k,
    const float* __restrict__ W1w, const float* __restrict__ b1w,
    const float* __restrict__ W1g, const float* __restrict__ b1g,
    const float* __restrict__ W1o, const float* __restrict__ b1o,
    const float* __restrict__ W2k, const float* __restrict__ b2k,
    const float* __restrict__ W2w, const float* __restrict__ b2w,
    const float* __restrict__ W2g, const float* __restrict__ b2g,
    float* __restrict__ P1, float* __restrict__ R1,
    float* __restrict__ P2, float* __restrict__ O1last, float* __restrict__ R2F,
    unsigned short* __restrict__ W1oTb, unsigned short* __restrict__ W2cTb,
    unsigned* __restrict__ flags)
{
  __shared__ __align__(16) char smem[40448];
  unsigned* proj_cnt  = flags;        // [32], target 16 tiles/chunk
  unsigned* r1_cnt    = flags + 32;   // [32], target 2 blocks
  unsigned* fused_cnt = flags + 64;   // [32], target 64 tiles/chunk
  unsigned* prep_cnt  = flags + 96;   // [1],  target NW
  int role = blockIdx.x;
  int tid = threadIdx.x;

  if (role < 2){ scan_role<1,1>(P1, R1, role, proj_cnt, 16, r1_cnt, smem); return; }
  if (role < 4){ scan_role<0,0>(P2, R2F, role-2, fused_cnt, 64, nullptr, smem); return; }

  int wid = role - 4;
  int NW = (int)gridDim.x - 4;

  // ---- prep: bf16 weight repack (nt stores -> L3; consumers fence once below) ----------
  {
    int NT = NW*320;
    int gthread = wid*320 + tid;
    for (int x = gthread; x < 65536; x += NT){
      int n = x >> 7, k = x & 127;
      st_nt(&W1oTb[x], f2bf(W1o[k*512 + n]));
    }
    for (int x = gthread; x < 8192; x += NT){
      int j = x >> 9, cc = x & 511;
      float v = 0.f;
      if (j < 3) v = W2k[cc*3+j];
      else if (j < 6) v = W2w[cc*3+j-3];
      else if (j < 9) v = W2g[cc*3+j-6];
      st_nt(&W2cTb[x], f2bf(v));
    }
    __syncthreads();
    if (tid == 0) flag_add(prep_cnt);
  }

  // ---- proj phase: tile i=(c*16+q) -> P1[i*576 + o] producer-contiguous ----------------
  {
    float* A  = (float*)smem;             // 64*132 floats
    float* Wc = (float*)(smem + 33792);   // 1536 floats
    float* bb = (float*)(smem + 39936);   // 9 floats
    for (int w_=tid; w_<1152; w_+=320){
      int k=w_/9, j=w_%9; float val;
      if (j<3) val=W1k[k*3+j]; else if (j<6) val=W1w[k*3+j-3]; else val=W1g[k*3+j-6];
      Wc[k*12+j]=val;
    }
    if (tid<9){ float v; if(tid<3)v=b1k[tid]; else if(tid<6)v=b1w[tid-3]; else v=b1g[tid-6]; bb[tid]=v; }
    __syncthreads();
    #pragma unroll 1
    for (int i = wid; i < 512; i += NW){   // 32 chunks x 16 quads
      int c = i >> 4, q = i & 15;
      if (tid < 256){
        #pragma unroll
        for (int it=0; it<8; ++it){
          int f4 = tid + it*256;
          int blk = f4 >> 9, off = f4 & 511;
          const float4* src = (const float4*)(X + ((long)(4*q+blk)*512 + 16*c)*128);
          float4 v = src[off];
          int f = off*4, trow = f>>7, k = f&127;
          int row = blk*16 + trow;
          A[row*132+k]=v.x; A[row*132+k+1]=v.y; A[row*132+k+2]=v.z; A[row*132+k+3]=v.w;
        }
      }
      __syncthreads();
      for (int o = tid; o < 576; o += 320){
        int row=o/9, j=o%9;
        float acc = bb[j];
        #pragma unroll 8
        for (int k=0;k<128;++k) acc = fmaf(A[row*132+k], Wc[k*12+j], acc);
        if (j<3) acc *= LOG2E;
        else if (j<6) acc *= 0.1f;
        else acc = 0.1f*sigmoidf_(acc);
        st_nt(&P1[(long)i*576 + o], acc);
      }
      __syncthreads();
      if (tid == 0) flag_add(&proj_cnt[c]);
    }
  }

  // ---- wait: all workers finished prep; ONE acquire per worker (only invalidates here) --
  if (tid == 0) spin_rlx<8>(prep_cnt, (unsigned)NW);
  __syncthreads();
  acq_fence();

  // ---- fused phase: tile i=(c*64+b) -> P2[i*144 + tid] producer-contiguous -------------
  {
    float* pSum = (float*)smem;                       // 1024 floats
    float* rdS  = (float*)(smem + 4096);              // 48 floats
    unsigned short* o1b = (unsigned short*)(smem + 4352);  // 16*520 shorts
    int w = tid >> 6, lane = tid & 63;
    int n16 = lane & 15, g4 = lane >> 4;
    #pragma unroll 1
    for (int i = wid; i < 2048; i += NW){
      int c = i >> 6, b = i & 63;
      if (tid == 0) spin_rlx<16>(&r1_cnt[c], 2);
      __syncthreads();
      int t0 = c*16;
      long r0 = (long)b*512 + t0;
      if (tid < 48){
        int ii = tid/3, d = tid%3;
        rdS[tid] = ld_rlx_f32(&R1[((t0+ii)*3+d)*64 + b]);
      }
      short8 afr[4];
      if (w < 4){
        const float* Xrow = X + (r0 + n16)*128;
        #pragma unroll
        for (int q=0;q<4;++q){
          f32x4 x0 = *(const f32x4*)(Xrow + q*32 + g4*8);
          f32x4 x1 = *(const f32x4*)(Xrow + q*32 + g4*8 + 4);
          short8 a;
          a[0]=(short)f2bf(x0[0]); a[1]=(short)f2bf(x0[1]);
          a[2]=(short)f2bf(x0[2]); a[3]=(short)f2bf(x0[3]);
          a[4]=(short)f2bf(x1[0]); a[5]=(short)f2bf(x1[1]);
          a[6]=(short)f2bf(x1[2]); a[7]=(short)f2bf(x1[3]);
          afr[q]=a;
        }
      }
      __syncthreads();
      if (w < 4){
        f32x4 ra = *(const f32x4*)(rdS + g4*12);
        f32x4 rb = *(const f32x4*)(rdS + g4*12 + 4);
        f32x4 rc = *(const f32x4*)(rdS + g4*12 + 8);
        float rd0[4] = { ra[0], ra[3], rb[2], rc[1] };
        float rd1[4] = { ra[1], rb[0], rb[3], rc[2] };
        float rd2[4] = { ra[2], rb[1], rc[0], rc[3] };
        #pragma unroll
        for (int tt=0; tt<8; ++tt){
          int gc = w*128 + tt*16 + n16;
          f32x4 acc = {0.f,0.f,0.f,0.f};
          #pragma unroll
          for (int q=0;q<4;++q){
            short8 bf = *(const short8*)(W1oTb + gc*128 + q*32 + g4*8);
            acc = __builtin_amdgcn_mfma_f32_16x16x32_bf16(afr[q], bf, acc, 0,0,0);
          }
          float bias = b1o[gc];
          float wr0 = W1o[128*512+gc], wr1 = W1o[129*512+gc], wr2 = W1o[130*512+gc];
          #pragma unroll
          for (int reg=0; reg<4; ++reg){
            int rowloc = g4*4 + reg;
            float z = acc[reg] + bias + rd0[reg]*wr0 + rd1[reg]*wr1 + rd2[reg]*wr2;
            float o1 = sigmoidf_(z);
            o1b[rowloc*520 + gc] = f2bf(o1);
            if (c == 31 && rowloc == 15) st_nt(&O1last[b*512 + gc], o1);
          }
        }
        f32x4 accP = {0.f,0.f,0.f,0.f};
        #pragma unroll
        for (int q2=0; q2<4; ++q2){
          int kk = w*128 + q2*32;
          short8 a2 = *(const short8*)(o1b + n16*520 + kk + g4*8);
          short8 bb2 = *(const short8*)(W2cTb + n16*512 + kk + g4*8);
          accP = __builtin_amdgcn_mfma_f32_16x16x32_bf16(a2, bb2, accP, 0,0,0);
        }
        #pragma unroll
        for (int reg=0;reg<4;++reg){
          int rowloc = g4*4+reg;
          pSum[w*256 + rowloc*16 + n16] = accP[reg];
        }
      }
      __syncthreads();
      if (tid < 144){
        int r = tid/9, j = tid%9;
        float s = pSum[r*16+j] + pSum[256+r*16+j] + pSum[512+r*16+j] + pSum[768+r*16+j];
        float outv;
        if (j<3){ s += b2k[j]; outv = s*LOG2E; }
        else if (j<6){ s += b2w[j-3]; outv = 0.1f*s; }
        else { s += b2g[j-6]; outv = 0.1f*sigmoidf_(s); }
        st_nt(&P2[(long)i*144 + tid], outv);
      }
      __syncthreads();
      if (tid == 0) flag_add(&fused_cnt[c]);
    }
  }
}

// ---------------- k_final: O1last@W2o + read2 correction + sigmoid ----------------------
__global__ __launch_bounds__(128) void k_final(const float* __restrict__ O1last,
    const float* __restrict__ R2F, const float* __restrict__ W2o,
    const float* __restrict__ b2o, float* __restrict__ out)
{
  __shared__ __align__(16) float s2[512];
  int b = blockIdx.x, tid = threadIdx.x;
  ((float4*)s2)[tid] = ((const float4*)(O1last + b*512))[tid];
  __syncthreads();
  float acc = b2o[tid];
  #pragma unroll 8
  for (int n=0;n<512;++n) acc = fmaf(s2[n], W2o[n*128+tid], acc);
  float r0 = R2F[b], r1 = R2F[64+b], r2 = R2F[128+b];
  acc += r0*W2o[512*128+tid] + r1*W2o[513*128+tid] + r2*W2o[514*128+tid];
  out[b*128+tid] = sigmoidf_(acc);
}

extern "C" void kernel_launch(void* const* d_in, const int* in_sizes, int n_in,
                              void* d_out, int out_size, void* d_ws, size_t ws_size,
                              hipStream_t stream)
{
  const float* X  = (const float*)d_in[0];
  const float* W1k= (const float*)d_in[1]; const float* b1k=(const float*)d_in[2];
  const float* W1w= (const float*)d_in[3]; const float* b1w=(const float*)d_in[4];
  const float* W1g= (const float*)d_in[5]; const float* b1g=(const float*)d_in[6];
  const float* W1o= (const float*)d_in[7]; const float* b1o=(const float*)d_in[8];
  const float* W2k= (const float*)d_in[9]; const float* b2k=(const float*)d_in[10];
  const float* W2w= (const float*)d_in[11]; const float* b2w=(const float*)d_in[12];
  const float* W2g= (const float*)d_in[13]; const float* b2g=(const float*)d_in[14];
  const float* W2o= (const float*)d_in[15]; const float* b2o=(const float*)d_in[16];

  float* ws = (float*)d_ws;
  float* P1     = ws;               // 512*576    = 294912 (tile-contiguous)
  float* R1     = P1 + 294912;      // 512*3*64   =  98304
  float* P2     = R1 + 98304;       // 2048*144   = 294912 (tile-contiguous)
  float* O1last = P2 + 294912;      // 64*512     =  32768
  float* R2F    = O1last + 32768;   // 3*64       =    192
  unsigned short* W1oTb = (unsigned short*)(R2F + 192);   // 512*128 bf16 = 32768 f
  unsigned short* W2cTb = W1oTb + 65536;                  // 16*512 bf16  =  4096 f
  unsigned* flags = (unsigned*)(R2F + 192 + 32768 + 4096);  // 128 u32
  float* out    = (float*)d_out;

  hipMemsetAsync(flags, 0, 512, stream);
  hipLaunchKernelGGL(k_mega, dim3(256), dim3(320), 0, stream,
                     X, W1k,b1k, W1w,b1w, W1g,b1g, W1o,b1o,
                     W2k,b2k, W2w,b2w, W2g,b2g,
                     P1, R1, P2, O1last, R2F, W1oTb, W2cTb, flags);
  hipLaunchKernelGGL(k_final, dim3(64), dim3(128), 0, stream,
                     O1last, R2F, W2o, b2o, out);
}